// Round 3
// baseline (316.051 us; speedup 1.0000x reference)
//
#include <hip/hip_runtime.h>
#include <hip/hip_fp16.h>

typedef _Float16 f16x8  __attribute__((ext_vector_type(8)));
typedef float    f32x4  __attribute__((ext_vector_type(4)));
typedef float    f32x16 __attribute__((ext_vector_type(16)));

#define BATCH 131072

// ---------------------------------------------------------------------------
// Kernel 1: synthesize W_i[k][n] = tri(dist(p_i[k], p_{i+1}[n])) / sqrt(K),
// stored TRANSPOSED as Wt[n][k] f16 (B-fragments = 8 contiguous k per lane).
// ---------------------------------------------------------------------------
__global__ void synth_weights_kernel(const float* __restrict__ p0, const float* __restrict__ p1,
                                     const float* __restrict__ p2, const float* __restrict__ p3,
                                     _Float16* __restrict__ wt0, _Float16* __restrict__ wt1,
                                     _Float16* __restrict__ wt2)
{
    int idx = blockIdx.x * blockDim.x + threadIdx.x;   // 524288 total, exact grid
    const float* A; const float* B; _Float16* Wt; int K, N; float scl; int e;
    if (idx < 131072)      { A = p0; B = p1; Wt = wt0; K = 256; N = 512; scl = 0.0625f;              e = idx; }
    else if (idx < 393216) { A = p1; B = p2; Wt = wt1; K = 512; N = 512; scl = 0.04419417382415922f; e = idx - 131072; }
    else                   { A = p2; B = p3; Wt = wt2; K = 512; N = 256; scl = 0.04419417382415922f; e = idx - 393216; }
    int k = e / N;
    int n = e - k * N;
    float d2 = 0.f;
#pragma unroll
    for (int t = 0; t < 20; ++t) {
        float df = A[k * 20 + t] - B[n * 20 + t];
        d2 += df * df;
    }
    float d  = sqrtf(d2);
    float md = fmodf(d, 0.2f);                            // period 2P = 0.2, d >= 0
    float w  = 10.0f * (0.05f - fabsf(md - 0.1f)) * scl;  // AMP/P*(P-|m-P|-P/2)/sqrt(K)
    Wt[(size_t)n * K + k] = (_Float16)w;
}

// ---------------------------------------------------------------------------
// Fused MLP, v2: 32x32x16 MFMA, big-step = 32 k (2 k-tiles), B-prefetch ring
// depth 2 big-steps. One block = 128 batch rows; activations in 128 KB LDS,
// XOR-swizzled 16B chunks (phys_chunk = chunk ^ (row&7)).
// 8 waves; wave tile 128m x 64n (L1/L2) or 128m x 32n (L3).
// ---------------------------------------------------------------------------

// A-frag (32x32x16): row = lane&31, k = (lane>>5)*8 + j (8 consecutive)
// B-frag:            col = lane&31, k = (lane>>5)*8 + j
// C/D:               col = lane&31, row = (reg&3) + 8*(reg>>2) + 4*(lane>>5)
template<int K, int LDROW, int NI>
__device__ __forceinline__ void mm32(const char* lds, const _Float16* __restrict__ Wt,
                                     int n0, int lane, f32x16 (&acc)[4][NI])
{
    constexpr int KT = K / 32;                 // big-steps (8 or 16, always even)
    const int rl = lane & 31;
    const int hi = lane >> 5;

    const _Float16* wp[NI];
#pragma unroll
    for (int ni = 0; ni < NI; ++ni)
        wp[ni] = Wt + (size_t)(n0 + ni * 32 + rl) * K + hi * 8;

    f16x8 bA[NI][2], bB[NI][2];
#pragma unroll
    for (int ni = 0; ni < NI; ++ni) {          // preload big-steps 0 and 1
        bA[ni][0] = *(const f16x8*)(wp[ni]);
        bA[ni][1] = *(const f16x8*)(wp[ni] + 16);
        bB[ni][0] = *(const f16x8*)(wp[ni] + 32);
        bB[ni][1] = *(const f16x8*)(wp[ni] + 48);
    }

#define MM32_BODY(S, BF)                                                          \
    {                                                                             \
        f16x8 af[4][2];                                                           \
        _Pragma("unroll")                                                         \
        for (int mi = 0; mi < 4; ++mi) {                                          \
            const int row = mi * 32 + rl;                                         \
            _Pragma("unroll")                                                     \
            for (int t = 0; t < 2; ++t) {                                         \
                const int c = (S) * 4 + t * 2 + hi;                               \
                af[mi][t] = *(const f16x8*)(lds + row * LDROW + ((c ^ (row & 7)) << 4)); \
            }                                                                     \
        }                                                                         \
        _Pragma("unroll")                                                         \
        for (int t = 0; t < 2; ++t)                                               \
            _Pragma("unroll")                                                     \
            for (int mi = 0; mi < 4; ++mi)                                        \
                _Pragma("unroll")                                                 \
                for (int ni = 0; ni < NI; ++ni)                                   \
                    acc[mi][ni] = __builtin_amdgcn_mfma_f32_32x32x16_f16(         \
                        af[mi][t], BF[ni][t], acc[mi][ni], 0, 0, 0);              \
        if ((S) + 2 < KT) {                                                       \
            _Pragma("unroll")                                                     \
            for (int ni = 0; ni < NI; ++ni) {                                     \
                BF[ni][0] = *(const f16x8*)(wp[ni] + ((S) + 2) * 32);             \
                BF[ni][1] = *(const f16x8*)(wp[ni] + ((S) + 2) * 32 + 16);        \
            }                                                                     \
        }                                                                         \
    }

#pragma unroll
    for (int ks = 0; ks < KT; ks += 2) {
        MM32_BODY(ks, bA)
        MM32_BODY(ks + 1, bB)
    }
#undef MM32_BODY
}

// Write z (bias+relu, f32->f16) into LDS [128][1024B], swizzled. Conflict-free
// with the 32x32 D layout (8 chunk positions -> all 32 banks, 2-way same-dword).
template<int NI>
__device__ __forceinline__ void store_z32(char* lds, const float* __restrict__ bias,
                                          int n0, int lane, f32x16 (&acc)[4][NI])
{
    const int rl = lane & 31;
    const int hi4 = (lane >> 5) * 4;
#pragma unroll
    for (int ni = 0; ni < NI; ++ni) {
        const int n  = n0 + ni * 32 + rl;
        const float bv = bias[n];
        const int chx = n >> 3;
        const int nb2 = (n & 7) * 2;
#pragma unroll
        for (int mi = 0; mi < 4; ++mi) {
#pragma unroll
            for (int r = 0; r < 16; ++r) {
                const int m = mi * 32 + (r & 3) + 8 * (r >> 2) + hi4;
                float v = fmaxf(acc[mi][ni][r] + bv, 0.0f);
                *(_Float16*)(lds + m * 1024 + (((chx ^ (m & 7))) << 4) + nb2) = (_Float16)v;
            }
        }
    }
}

__global__ __launch_bounds__(512, 2)
void fused_mlp_kernel(const float* __restrict__ x,
                      const _Float16* __restrict__ wt0, const _Float16* __restrict__ wt1,
                      const _Float16* __restrict__ wt2,
                      const float* __restrict__ b1, const float* __restrict__ b2,
                      const float* __restrict__ b3,
                      float* __restrict__ out)
{
    extern __shared__ char lds[];
    const int tid  = threadIdx.x;
    const int lane = tid & 63;
    const int w    = tid >> 6;
    const size_t m0 = (size_t)blockIdx.x * 128;

    // ---- stage x slab f32 -> f16 into LDS [128 rows][512 B], swizzled
#pragma unroll
    for (int it = 0; it < 8; ++it) {
        const int c   = it * 512 + tid;
        const int row = c >> 5;
        const int c8  = c & 31;
        const float* src = x + (m0 + row) * 256 + c8 * 8;
        const float4 v0 = *(const float4*)src;
        const float4 v1 = *(const float4*)(src + 4);
        f16x8 h;
        h[0] = (_Float16)v0.x; h[1] = (_Float16)v0.y; h[2] = (_Float16)v0.z; h[3] = (_Float16)v0.w;
        h[4] = (_Float16)v1.x; h[5] = (_Float16)v1.y; h[6] = (_Float16)v1.z; h[7] = (_Float16)v1.w;
        *(f16x8*)(lds + row * 512 + ((c8 ^ (row & 7)) << 4)) = h;
    }
    __syncthreads();

    // ---- layer 1: z1 = relu(x @ W0 + b1)   [128,256]@[256,512]
    {
        f32x16 acc[4][2] = {};
        mm32<256, 512, 2>(lds, wt0, w * 64, lane, acc);
        __syncthreads();                       // all waves done reading x
        store_z32<2>(lds, b1, w * 64, lane, acc);
        __syncthreads();
    }

    // ---- layer 2: z2 = relu(z1 @ W1 + b2)  [128,512]@[512,512]  (in-place)
    {
        f32x16 acc[4][2] = {};
        mm32<512, 1024, 2>(lds, wt1, w * 64, lane, acc);
        __syncthreads();
        store_z32<2>(lds, b2, w * 64, lane, acc);
        __syncthreads();
    }

    // ---- layer 3: out = z2 @ W2 + b3       [128,512]@[512,256], f32
    {
        f32x16 acc[4][1] = {};
        mm32<512, 1024, 1>(lds, wt2, w * 32, lane, acc);
        __syncthreads();                       // done reading z2

        // stage out slab f32 into LDS [128][1024B], swizzled 16B chunks
        const int rl = lane & 31;
        const int hi4 = (lane >> 5) * 4;
        const int n = w * 32 + rl;
        const float bv = b3[n];
        const int chx = n >> 2;
        const int nb4 = (n & 3) * 4;
#pragma unroll
        for (int mi = 0; mi < 4; ++mi) {
#pragma unroll
            for (int r = 0; r < 16; ++r) {
                const int m = mi * 32 + (r & 3) + 8 * (r >> 2) + hi4;
                *(float*)(lds + m * 1024 + ((chx ^ (m & 7)) << 4) + nb4) = acc[mi][0][r] + bv;
            }
        }
        __syncthreads();

        // coalesced write-back: one wave-instr = 1 KB contiguous (one out row)
#pragma unroll
        for (int it = 0; it < 16; ++it) {
            const int idx = it * 512 + tid;
            const int row = idx >> 6;
            const int c   = idx & 63;
            const f32x4 v = *(const f32x4*)(lds + row * 1024 + ((c ^ (row & 7)) << 4));
            *(f32x4*)(out + (m0 + row) * 256 + c * 4) = v;
        }
    }
}

// ---------------------------------------------------------------------------
// kernel_launch — ws: [wt0 512x256 f16 | wt1 512x512 f16 | wt2 256x512 f16]
// ---------------------------------------------------------------------------
extern "C" void kernel_launch(void* const* d_in, const int* in_sizes, int n_in,
                              void* d_out, int out_size, void* d_ws, size_t ws_size,
                              hipStream_t stream)
{
    const float* x  = (const float*)d_in[0];
    const float* p0 = (const float*)d_in[1];
    const float* p1 = (const float*)d_in[2];
    const float* p2 = (const float*)d_in[3];
    const float* p3 = (const float*)d_in[4];
    const float* b1 = (const float*)d_in[5];
    const float* b2 = (const float*)d_in[6];
    const float* b3 = (const float*)d_in[7];

    char* ws = (char*)d_ws;
    _Float16* wt0 = (_Float16*)(ws);                    // 262144 B
    _Float16* wt1 = (_Float16*)(ws + 262144);           // 524288 B
    _Float16* wt2 = (_Float16*)(ws + 262144 + 524288);  // 262144 B

    synth_weights_kernel<<<2048, 256, 0, stream>>>(p0, p1, p2, p3, wt0, wt1, wt2);

    fused_mlp_kernel<<<BATCH / 128, 512, 131072, stream>>>(x, wt0, wt1, wt2, b1, b2, b3,
                                                           (float*)d_out);
}

// Round 4
// 302.736 us; speedup vs baseline: 1.0440x; 1.0440x over previous
//
#include <hip/hip_runtime.h>
#include <hip/hip_fp16.h>

typedef _Float16 f16x8 __attribute__((ext_vector_type(8)));
typedef float    f32x4 __attribute__((ext_vector_type(4)));

#define BATCH 131072

// ---------------------------------------------------------------------------
// Kernel 1: synthesize W_i[k][n] = tri(dist(p_i[k], p_{i+1}[n])) / sqrt(K),
// stored TRANSPOSED as Wt[n][k] f16 (B-fragments = 8 contiguous k per lane).
// ---------------------------------------------------------------------------
__global__ void synth_weights_kernel(const float* __restrict__ p0, const float* __restrict__ p1,
                                     const float* __restrict__ p2, const float* __restrict__ p3,
                                     _Float16* __restrict__ wt0, _Float16* __restrict__ wt1,
                                     _Float16* __restrict__ wt2)
{
    int idx = blockIdx.x * blockDim.x + threadIdx.x;   // 524288 total, exact grid
    const float* A; const float* B; _Float16* Wt; int K, N; float scl; int e;
    if (idx < 131072)      { A = p0; B = p1; Wt = wt0; K = 256; N = 512; scl = 0.0625f;              e = idx; }
    else if (idx < 393216) { A = p1; B = p2; Wt = wt1; K = 512; N = 512; scl = 0.04419417382415922f; e = idx - 131072; }
    else                   { A = p2; B = p3; Wt = wt2; K = 512; N = 256; scl = 0.04419417382415922f; e = idx - 393216; }
    int k = e / N;
    int n = e - k * N;
    float d2 = 0.f;
#pragma unroll
    for (int t = 0; t < 20; ++t) {
        float df = A[k * 20 + t] - B[n * 20 + t];
        d2 += df * df;
    }
    float d  = sqrtf(d2);
    float md = fmodf(d, 0.2f);                            // period 2P = 0.2, d >= 0
    float w  = 10.0f * (0.05f - fabsf(md - 0.1f)) * scl;  // AMP/P*(P-|m-P|-P/2)/sqrt(K)
    Wt[(size_t)n * K + k] = (_Float16)w;
}

// ---------------------------------------------------------------------------
// Fused MLP v3: 64 batch rows per block, 64 KB LDS -> 2 blocks/CU (4 w/SIMD).
// 16x16x32 MFMA; activations XOR-swizzled in 16B chunks (phys = c ^ (row&7)).
// 8 waves; wave tile 64m x 64n (L1/L2) or 64m x 32n (L3). acc = 64 f32/lane.
// Weights read straight from L2 as per-lane 16B B-fragments (no LDS staging).
// ---------------------------------------------------------------------------

// A-frag (16x16x32): row = lane&15, k = (lane>>4)*8 + j
// B-frag:            col = lane&15, k = (lane>>4)*8 + j
// C/D:               col = lane&15, row = (lane>>4)*4 + q   [HW-verified]
template<int K, int LDROW, int NI>
__device__ __forceinline__ void mm16(const char* lds, const _Float16* __restrict__ Wt,
                                     int n0, int lane, f32x4 (&acc)[4][NI])
{
    constexpr int KT = K / 32;
    const int rl = lane & 15;
    const int kc = lane >> 4;                  // k-chunk 0..3

    const _Float16* wp[NI];
#pragma unroll
    for (int ni = 0; ni < NI; ++ni)
        wp[ni] = Wt + (size_t)(n0 + ni * 16 + rl) * K + kc * 8;

#pragma unroll 2
    for (int ks = 0; ks < KT; ++ks) {
        f16x8 bf[NI];
#pragma unroll
        for (int ni = 0; ni < NI; ++ni)
            bf[ni] = *(const f16x8*)(wp[ni] + ks * 32);
        f16x8 af[4];
#pragma unroll
        for (int mi = 0; mi < 4; ++mi) {
            const int row = mi * 16 + rl;
            const int c   = ks * 4 + kc;
            af[mi] = *(const f16x8*)(lds + row * LDROW + ((c ^ (row & 7)) << 4));
        }
#pragma unroll
        for (int mi = 0; mi < 4; ++mi)
#pragma unroll
            for (int ni = 0; ni < NI; ++ni)
                acc[mi][ni] = __builtin_amdgcn_mfma_f32_16x16x32_f16(af[mi], bf[ni], acc[mi][ni], 0, 0, 0);
    }
}

// Write z (bias+relu, f32->f16) into LDS [64][1024B], swizzled 16B chunks.
template<int NI>
__device__ __forceinline__ void store_z16(char* lds, const float* __restrict__ bias,
                                          int n0, int lane, f32x4 (&acc)[4][NI])
{
    const int rl = lane & 15;
    const int r4 = (lane >> 4) << 2;
#pragma unroll
    for (int ni = 0; ni < NI; ++ni) {
        const int n   = n0 + ni * 16 + rl;
        const float bv = bias[n];
        const int chx = n >> 3;
        const int nb2 = (n & 7) * 2;
#pragma unroll
        for (int mi = 0; mi < 4; ++mi) {
#pragma unroll
            for (int q = 0; q < 4; ++q) {
                const int m = mi * 16 + r4 + q;
                float v = fmaxf(acc[mi][ni][q] + bv, 0.0f);
                *(_Float16*)(lds + m * 1024 + ((chx ^ (m & 7)) << 4) + nb2) = (_Float16)v;
            }
        }
    }
}

__global__ __launch_bounds__(512, 4)
void fused_mlp_kernel(const float* __restrict__ x,
                      const _Float16* __restrict__ wt0, const _Float16* __restrict__ wt1,
                      const _Float16* __restrict__ wt2,
                      const float* __restrict__ b1, const float* __restrict__ b2,
                      const float* __restrict__ b3,
                      float* __restrict__ out)
{
    extern __shared__ char lds[];              // 64 KB
    const int tid  = threadIdx.x;
    const int lane = tid & 63;
    const int w    = tid >> 6;
    const size_t m0 = (size_t)blockIdx.x * 64;

    // ---- stage x slab f32 -> f16 into LDS [64 rows][512 B], swizzled
#pragma unroll
    for (int it = 0; it < 4; ++it) {
        const int c   = it * 512 + tid;        // 2048 16B-chunks total
        const int row = c >> 5;
        const int c8  = c & 31;
        const float* src = x + (m0 + row) * 256 + c8 * 8;
        const float4 v0 = *(const float4*)src;
        const float4 v1 = *(const float4*)(src + 4);
        f16x8 h;
        h[0] = (_Float16)v0.x; h[1] = (_Float16)v0.y; h[2] = (_Float16)v0.z; h[3] = (_Float16)v0.w;
        h[4] = (_Float16)v1.x; h[5] = (_Float16)v1.y; h[6] = (_Float16)v1.z; h[7] = (_Float16)v1.w;
        *(f16x8*)(lds + row * 512 + ((c8 ^ (row & 7)) << 4)) = h;
    }
    __syncthreads();

    // ---- layer 1: z1 = relu(x @ W0 + b1)   [64,256]@[256,512]
    {
        f32x4 acc[4][4] = {};
        mm16<256, 512, 4>(lds, wt0, w * 64, lane, acc);
        __syncthreads();                       // all waves done reading x
        store_z16<4>(lds, b1, w * 64, lane, acc);
        __syncthreads();
    }

    // ---- layer 2: z2 = relu(z1 @ W1 + b2)  [64,512]@[512,512]  (in-place)
    {
        f32x4 acc[4][4] = {};
        mm16<512, 1024, 4>(lds, wt1, w * 64, lane, acc);
        __syncthreads();
        store_z16<4>(lds, b2, w * 64, lane, acc);
        __syncthreads();
    }

    // ---- layer 3: out = z2 @ W2 + b3       [64,512]@[512,256], f32
    {
        f32x4 acc[4][2] = {};
        mm16<512, 1024, 2>(lds, wt2, w * 32, lane, acc);
        __syncthreads();                       // done reading z2

        // stage out slab f32 into LDS [64][1024B], swizzled 16B chunks
        const int rl = lane & 15;
        const int r4 = (lane >> 4) << 2;
#pragma unroll
        for (int ni = 0; ni < 2; ++ni) {
            const int n   = w * 32 + ni * 16 + rl;
            const float bv = b3[n];
            const int chx = n >> 2;
            const int nb4 = (n & 3) * 4;
#pragma unroll
            for (int mi = 0; mi < 4; ++mi) {
#pragma unroll
                for (int q = 0; q < 4; ++q) {
                    const int m = mi * 16 + r4 + q;
                    *(float*)(lds + m * 1024 + ((chx ^ (m & 7)) << 4) + nb4) = acc[mi][ni][q] + bv;
                }
            }
        }
        __syncthreads();

        // coalesced write-back: 64 rows x 1 KB, 16B/lane contiguous
#pragma unroll
        for (int it = 0; it < 8; ++it) {
            const int idx = it * 512 + tid;    // 4096 f32x4-slots
            const int row = idx >> 6;
            const int c   = idx & 63;
            const f32x4 v = *(const f32x4*)(lds + row * 1024 + ((c ^ (row & 7)) << 4));
            *(f32x4*)(out + (m0 + row) * 256 + c * 4) = v;
        }
    }
}

// ---------------------------------------------------------------------------
// kernel_launch — ws: [wt0 512x256 f16 | wt1 512x512 f16 | wt2 256x512 f16]
// ---------------------------------------------------------------------------
extern "C" void kernel_launch(void* const* d_in, const int* in_sizes, int n_in,
                              void* d_out, int out_size, void* d_ws, size_t ws_size,
                              hipStream_t stream)
{
    const float* x  = (const float*)d_in[0];
    const float* p0 = (const float*)d_in[1];
    const float* p1 = (const float*)d_in[2];
    const float* p2 = (const float*)d_in[3];
    const float* p3 = (const float*)d_in[4];
    const float* b1 = (const float*)d_in[5];
    const float* b2 = (const float*)d_in[6];
    const float* b3 = (const float*)d_in[7];

    char* ws = (char*)d_ws;
    _Float16* wt0 = (_Float16*)(ws);                    // 262144 B
    _Float16* wt1 = (_Float16*)(ws + 262144);           // 524288 B
    _Float16* wt2 = (_Float16*)(ws + 262144 + 524288);  // 262144 B

    synth_weights_kernel<<<2048, 256, 0, stream>>>(p0, p1, p2, p3, wt0, wt1, wt2);

    fused_mlp_kernel<<<BATCH / 64, 512, 65536, stream>>>(x, wt0, wt1, wt2, b1, b2, b3,
                                                         (float*)d_out);
}

// Round 5
// 233.718 us; speedup vs baseline: 1.3523x; 1.2953x over previous
//
#include <hip/hip_runtime.h>
#include <hip/hip_fp16.h>

typedef _Float16 f16x8 __attribute__((ext_vector_type(8)));
typedef _Float16 f16x4 __attribute__((ext_vector_type(4)));
typedef float    f32x4 __attribute__((ext_vector_type(4)));

#define BATCH 131072

// ---------------------------------------------------------------------------
// Kernel 1: synthesize W_i[k][n] = tri(dist(p_i[k], p_{i+1}[n])) / sqrt(K),
// stored TRANSPOSED as Wt[n][k] f16. k fast-varying -> coalesced writes.
// ---------------------------------------------------------------------------
__global__ void synth_weights_kernel(const float* __restrict__ p0, const float* __restrict__ p1,
                                     const float* __restrict__ p2, const float* __restrict__ p3,
                                     _Float16* __restrict__ wt0, _Float16* __restrict__ wt1,
                                     _Float16* __restrict__ wt2)
{
    int idx = blockIdx.x * blockDim.x + threadIdx.x;   // 524288 total, exact grid
    const float* A; const float* B; _Float16* Wt; float scl; int e, k, n;
    if (idx < 131072)      { A = p0; B = p1; Wt = wt0; scl = 0.0625f;              e = idx;          k = e & 255; n = e >> 8; }
    else if (idx < 393216) { A = p1; B = p2; Wt = wt1; scl = 0.04419417382415922f; e = idx - 131072; k = e & 511; n = e >> 9; }
    else                   { A = p2; B = p3; Wt = wt2; scl = 0.04419417382415922f; e = idx - 393216; k = e & 511; n = e >> 9; }
    float d2 = 0.f;
#pragma unroll
    for (int t = 0; t < 20; ++t) {
        float df = A[k * 20 + t] - B[n * 20 + t];
        d2 += df * df;
    }
    float d  = sqrtf(d2);
    float md = fmodf(d, 0.2f);                            // period 2P = 0.2, d >= 0
    float w  = 10.0f * (0.05f - fabsf(md - 0.1f)) * scl;  // AMP/P*(P-|m-P|-P/2)/sqrt(K)
    Wt[(size_t)e] = (_Float16)w;                          // e == n*K + k
}

// ---------------------------------------------------------------------------
// Fused MLP v5 (m97-style): 1024 threads, 128 rows/block.
// LDS: act [128 rows][1024 B] swizzled (128 KB) + W-window [N][32k] (32 KB).
// k-loop in 32-k windows: global_load_lds stage -> barrier -> ds_read_b128
// frags -> MFMA (swapped operands: D holds 4 consecutive n per lane).
// act chunk swizzle: phys = c ^ (row&7). W-window row = 64 B, 4 chunks,
// chunk swizzle: phys = kc ^ ((n ^ (n>>2)) & 3).
// ---------------------------------------------------------------------------

// frag layouts (16x16x32, HW-verified in R1-R4):
//   A/B input: index = lane&15, k = (lane>>4)*8 + j
//   D (swapped, D = W^T-frag x x-frag): m = lane&15, n = (lane>>4)*4 + q (+16ni)
template<int K, int ASTRIDE, int NI, int MI, int N>
__device__ __forceinline__ void mm_phase(const char* act, char* bwin,
                                         const _Float16* __restrict__ Wt,
                                         int wr, int wc, int tid, f32x4 (&acc)[NI][MI])
{
    const int lane = tid & 63;
    const int wid  = tid >> 6;
    const int rl = lane & 15;
    const int hi = lane >> 4;
    constexpr int NW = K / 32;            // 32-k windows
    constexpr int NISSUE = N / 16;        // 1 KB issues per window
    const int ln = lane >> 2;             // n-sub within 16-row group
    const int lp = lane & 3;              // physical chunk slot

#pragma unroll 1
    for (int w = 0; w < NW; ++w) {
        // ---- stage W window w: linear LDS dest, pre-swizzled global source
        for (int s = wid; s < NISSUE; s += 16) {
            const int n  = s * 16 + ln;
            const int kc = lp ^ ((n ^ (n >> 2)) & 3);
            const _Float16* src = Wt + (size_t)n * K + w * 32 + kc * 8;
            __builtin_amdgcn_global_load_lds((const __attribute__((address_space(1))) void*)src,
                                             (__attribute__((address_space(3))) void*)(bwin + s * 1024 + lane * 16),
                                             16, 0, 0);
        }
        __syncthreads();                  // vmcnt(0) drained by compiler before barrier

        f16x8 wf[NI], xf[MI];
#pragma unroll
        for (int ni = 0; ni < NI; ++ni) {
            const int n = wc + ni * 16 + rl;
            wf[ni] = *(const f16x8*)(bwin + n * 64 + ((hi ^ ((n ^ (n >> 2)) & 3)) << 4));
        }
#pragma unroll
        for (int mi = 0; mi < MI; ++mi) {
            const int row = wr + mi * 16 + rl;
            const int c   = w * 4 + hi;
            xf[mi] = *(const f16x8*)(act + row * ASTRIDE + ((c ^ (row & 7)) << 4));
        }
#pragma unroll
        for (int ni = 0; ni < NI; ++ni)
#pragma unroll
            for (int mi = 0; mi < MI; ++mi)
                acc[ni][mi] = __builtin_amdgcn_mfma_f32_16x16x32_f16(wf[ni], xf[mi], acc[ni][mi], 0, 0, 0);
        __syncthreads();                  // window consumed; safe to overwrite
    }
}

// Write z (bias+relu) into act LDS [128][1024B] as 8B packs of 4 consecutive n.
template<int NI, int MI>
__device__ __forceinline__ void store_z(char* act, const float* __restrict__ bias,
                                        int wr, int wc, int lane, f32x4 (&acc)[NI][MI])
{
    const int rl = lane & 15;
    const int hi = lane >> 4;
#pragma unroll
    for (int ni = 0; ni < NI; ++ni) {
        const int n0 = wc + ni * 16 + hi * 4;
        const float4 bv = *(const float4*)(bias + n0);
#pragma unroll
        for (int mi = 0; mi < MI; ++mi) {
            const int m = wr + mi * 16 + rl;
            f16x4 h;
            h[0] = (_Float16)fmaxf(acc[ni][mi][0] + bv.x, 0.0f);
            h[1] = (_Float16)fmaxf(acc[ni][mi][1] + bv.y, 0.0f);
            h[2] = (_Float16)fmaxf(acc[ni][mi][2] + bv.z, 0.0f);
            h[3] = (_Float16)fmaxf(acc[ni][mi][3] + bv.w, 0.0f);
            *(f16x4*)(act + m * 1024 + (((n0 >> 3) ^ (m & 7)) << 4) + (n0 & 7) * 2) = h;
        }
    }
}

__global__ __launch_bounds__(1024, 4)
void fused_mlp_kernel(const float* __restrict__ x,
                      const _Float16* __restrict__ wt0, const _Float16* __restrict__ wt1,
                      const _Float16* __restrict__ wt2,
                      const float* __restrict__ b1, const float* __restrict__ b2,
                      const float* __restrict__ b3,
                      float* __restrict__ out)
{
    extern __shared__ char lds[];             // 160 KB: act 128 KB | W-window 32 KB
    char* act  = lds;
    char* bwin = lds + 131072;
    const int tid  = threadIdx.x;
    const int lane = tid & 63;
    const int wid  = tid >> 6;
    const size_t m0 = (size_t)blockIdx.x * 128;

    // ---- stage x slab f32 -> f16 into act [128 rows][512 B], swizzled
#pragma unroll
    for (int it = 0; it < 4; ++it) {
        const int c   = it * 1024 + tid;      // 4096 16B-chunks
        const int row = c >> 5;
        const int c8  = c & 31;
        const float* src = x + (m0 + row) * 256 + c8 * 8;
        const float4 v0 = *(const float4*)src;
        const float4 v1 = *(const float4*)(src + 4);
        f16x8 h;
        h[0] = (_Float16)v0.x; h[1] = (_Float16)v0.y; h[2] = (_Float16)v0.z; h[3] = (_Float16)v0.w;
        h[4] = (_Float16)v1.x; h[5] = (_Float16)v1.y; h[6] = (_Float16)v1.z; h[7] = (_Float16)v1.w;
        *(f16x8*)(act + row * 512 + ((c8 ^ (row & 7)) << 4)) = h;
    }
    __syncthreads();

    // wave tiling L1/L2: 16 waves = 2m x 8n of (64m x 64n)
    const int wr = (wid >> 3) * 64;
    const int wc = (wid & 7) * 64;

    // ---- layer 1: z1 = relu(x @ W0 + b1)   [128,256]@[256,512]
    {
        f32x4 acc[4][4] = {};
        mm_phase<256, 512, 4, 4, 512>(act, bwin, wt0, wr, wc, tid, acc);
        store_z(act, b1, wr, wc, lane, acc);  // overwrites x region (all reads done)
        __syncthreads();
    }

    // ---- layer 2: z2 = relu(z1 @ W1 + b2)  [128,512]@[512,512]  (in-place)
    {
        f32x4 acc[4][4] = {};
        mm_phase<512, 1024, 4, 4, 512>(act, bwin, wt1, wr, wc, tid, acc);
        store_z(act, b2, wr, wc, lane, acc);
        __syncthreads();
    }

    // ---- layer 3: out = z2 @ W2 + b3       [128,512]@[512,256], direct f32 store
    {
        const int wr3 = (wid & 3) * 32;       // 4m x 4n of (32m x 64n)
        const int wc3 = (wid >> 2) * 64;
        f32x4 acc[4][2] = {};
        mm_phase<512, 1024, 4, 2, 256>(act, bwin, wt2, wr3, wc3, tid, acc);

        const int rl = lane & 15;
        const int hi = lane >> 4;
#pragma unroll
        for (int ni = 0; ni < 4; ++ni) {
            const int n0 = wc3 + ni * 16 + hi * 4;
            const float4 bv = *(const float4*)(b3 + n0);
#pragma unroll
            for (int mi = 0; mi < 2; ++mi) {
                const size_t m = m0 + wr3 + mi * 16 + rl;
                f32x4 o;
                o[0] = acc[ni][mi][0] + bv.x;
                o[1] = acc[ni][mi][1] + bv.y;
                o[2] = acc[ni][mi][2] + bv.z;
                o[3] = acc[ni][mi][3] + bv.w;
                *(f32x4*)(out + m * 256 + n0) = o;
            }
        }
    }
}

// ---------------------------------------------------------------------------
// kernel_launch — ws: [wt0 512x256 f16 | wt1 512x512 f16 | wt2 256x512 f16]
// ---------------------------------------------------------------------------
extern "C" void kernel_launch(void* const* d_in, const int* in_sizes, int n_in,
                              void* d_out, int out_size, void* d_ws, size_t ws_size,
                              hipStream_t stream)
{
    const float* x  = (const float*)d_in[0];
    const float* p0 = (const float*)d_in[1];
    const float* p1 = (const float*)d_in[2];
    const float* p2 = (const float*)d_in[3];
    const float* p3 = (const float*)d_in[4];
    const float* b1 = (const float*)d_in[5];
    const float* b2 = (const float*)d_in[6];
    const float* b3 = (const float*)d_in[7];

    char* ws = (char*)d_ws;
    _Float16* wt0 = (_Float16*)(ws);                    // 262144 B
    _Float16* wt1 = (_Float16*)(ws + 262144);           // 524288 B
    _Float16* wt2 = (_Float16*)(ws + 262144 + 524288);  // 262144 B

    synth_weights_kernel<<<2048, 256, 0, stream>>>(p0, p1, p2, p3, wt0, wt1, wt2);

    fused_mlp_kernel<<<BATCH / 128, 1024, 163840, stream>>>(x, wt0, wt1, wt2, b1, b2, b3,
                                                            (float*)d_out);
}

// Round 6
// 198.197 us; speedup vs baseline: 1.5946x; 1.1792x over previous
//
#include <hip/hip_runtime.h>
#include <hip/hip_fp16.h>

typedef _Float16 f16x8 __attribute__((ext_vector_type(8)));
typedef _Float16 f16x4 __attribute__((ext_vector_type(4)));
typedef float    f32x4 __attribute__((ext_vector_type(4)));

#define BATCH 131072

// ---------------------------------------------------------------------------
// Kernel 1: synthesize W_i[k][n] = tri(dist(p_i[k], p_{i+1}[n])) / sqrt(K),
// stored TRANSPOSED as Wt[n][k] f16. k fast-varying -> coalesced writes.
// ---------------------------------------------------------------------------
__global__ void synth_weights_kernel(const float* __restrict__ p0, const float* __restrict__ p1,
                                     const float* __restrict__ p2, const float* __restrict__ p3,
                                     _Float16* __restrict__ wt0, _Float16* __restrict__ wt1,
                                     _Float16* __restrict__ wt2)
{
    int idx = blockIdx.x * blockDim.x + threadIdx.x;   // 524288 total, exact grid
    const float* A; const float* B; _Float16* Wt; float scl; int e, k, n;
    if (idx < 131072)      { A = p0; B = p1; Wt = wt0; scl = 0.0625f;              e = idx;          k = e & 255; n = e >> 8; }
    else if (idx < 393216) { A = p1; B = p2; Wt = wt1; scl = 0.04419417382415922f; e = idx - 131072; k = e & 511; n = e >> 9; }
    else                   { A = p2; B = p3; Wt = wt2; scl = 0.04419417382415922f; e = idx - 393216; k = e & 511; n = e >> 9; }
    float d2 = 0.f;
#pragma unroll
    for (int t = 0; t < 20; ++t) {
        float df = A[k * 20 + t] - B[n * 20 + t];
        d2 += df * df;
    }
    float d  = sqrtf(d2);
    float md = fmodf(d, 0.2f);                            // period 2P = 0.2, d >= 0
    float w  = 10.0f * (0.05f - fabsf(md - 0.1f)) * scl;  // AMP/P*(P-|m-P|-P/2)/sqrt(K)
    Wt[(size_t)e] = (_Float16)w;                          // e == n*K + k
}

// ---------------------------------------------------------------------------
// Fused MLP v6: 1024 threads, 128 rows/block, LDS = act 128 KB + bwin 32 KB.
// Weight windows staged via REGISTER prefetch (issue window w+1 before w's
// MFMA cluster; ds_write after the post-MFMA barrier -> vmcnt hidden under
// compute). setprio(1) around MFMAs. L1/L2: WK=32 (bwin rows 64 B, swizzle
// q4 = (n^(n>>2))&3). L3: WK=64 (rows 128 B, swizzle q8 = (n^(n>>3))&7).
// Act slab rows 1024 B, chunk swizzle c ^ (row&7). All reads 2-way minimal.
// ---------------------------------------------------------------------------
template<int K, int WK, int NI, int MI, int N>
__device__ __forceinline__ void mm_phase(const char* act, char* bwin,
                                         const _Float16* __restrict__ Wt,
                                         int wr, int wc, int tid, f32x4 (&acc)[NI][MI])
{
    constexpr int NW  = K / WK;          // windows
    constexpr int CH  = WK / 8;          // 16B chunks per bwin row (4 or 8)
    constexpr int RPI = 64 / CH;         // rows per write-instr
    constexpr int TS  = WK / 32;         // MFMA k-steps per window
    const int lane = tid & 63;
    const int wid  = tid >> 6;
    const int rl = lane & 15;
    const int hi = lane >> 4;

    // staging geometry: 2 instrs/wave/window, per-lane constant src/dst
    const int wrow = lane / CH;
    const int wcc  = lane % CH;          // logical chunk
    const _Float16* pfsrc[2];
    char* pfdst[2];
#pragma unroll
    for (int j = 0; j < 2; ++j) {
        const int n = wid * (2 * RPI) + j * RPI + wrow;
        const int q = (CH == 4) ? ((n ^ (n >> 2)) & 3) : ((n ^ (n >> 3)) & 7);
        pfsrc[j] = Wt + (size_t)n * K + wcc * 8;
        pfdst[j] = bwin + n * (2 * WK) + ((wcc ^ q) << 4);
    }

    // prologue: stage window 0
    f16x8 pf0 = *(const f16x8*)(pfsrc[0]);
    f16x8 pf1 = *(const f16x8*)(pfsrc[1]);
    *(f16x8*)pfdst[0] = pf0;
    *(f16x8*)pfdst[1] = pf1;
    __syncthreads();

#pragma unroll 1
    for (int w = 0; w < NW; ++w) {
        // ---- fragment reads for window w
        f16x8 wf[NI][TS], xf[MI][TS];
#pragma unroll
        for (int ni = 0; ni < NI; ++ni) {
            const int n = wc + ni * 16 + rl;
            const int q = (CH == 4) ? ((n ^ (n >> 2)) & 3) : ((n ^ (n >> 3)) & 7);
#pragma unroll
            for (int t = 0; t < TS; ++t)
                wf[ni][t] = *(const f16x8*)(bwin + n * (2 * WK) + (((t * 4 + hi) ^ q) << 4));
        }
#pragma unroll
        for (int mi = 0; mi < MI; ++mi) {
            const int row = wr + mi * 16 + rl;
#pragma unroll
            for (int t = 0; t < TS; ++t) {
                const int c = w * CH + t * 4 + hi;
                xf[mi][t] = *(const f16x8*)(act + row * 1024 + ((c ^ (row & 7)) << 4));
            }
        }
        // ---- issue global prefetch of window w+1 (latency hides under MFMA)
        if (w + 1 < NW) {
            pf0 = *(const f16x8*)(pfsrc[0] + (size_t)(w + 1) * WK);
            pf1 = *(const f16x8*)(pfsrc[1] + (size_t)(w + 1) * WK);
        }
        // ---- MFMA cluster
        __builtin_amdgcn_s_setprio(1);
#pragma unroll
        for (int t = 0; t < TS; ++t)
#pragma unroll
            for (int ni = 0; ni < NI; ++ni)
#pragma unroll
                for (int mi = 0; mi < MI; ++mi)
                    acc[ni][mi] = __builtin_amdgcn_mfma_f32_16x16x32_f16(wf[ni][t], xf[mi][t], acc[ni][mi], 0, 0, 0);
        __builtin_amdgcn_s_setprio(0);
        __syncthreads();                 // all waves done reading bwin window w
        if (w + 1 < NW) {
            *(f16x8*)pfdst[0] = pf0;     // vmcnt satisfied long ago
            *(f16x8*)pfdst[1] = pf1;
            __syncthreads();             // window w+1 visible
        }
    }
}

// Write z (bias+relu) into act LDS [128][1024B] as 8B packs of 4 consecutive n.
template<int NI, int MI>
__device__ __forceinline__ void store_z(char* act, const float* __restrict__ bias,
                                        int wr, int wc, int lane, f32x4 (&acc)[NI][MI])
{
    const int rl = lane & 15;
    const int hi = lane >> 4;
#pragma unroll
    for (int ni = 0; ni < NI; ++ni) {
        const int n0 = wc + ni * 16 + hi * 4;
        const float4 bv = *(const float4*)(bias + n0);
#pragma unroll
        for (int mi = 0; mi < MI; ++mi) {
            const int m = wr + mi * 16 + rl;
            f16x4 h;
            h[0] = (_Float16)fmaxf(acc[ni][mi][0] + bv.x, 0.0f);
            h[1] = (_Float16)fmaxf(acc[ni][mi][1] + bv.y, 0.0f);
            h[2] = (_Float16)fmaxf(acc[ni][mi][2] + bv.z, 0.0f);
            h[3] = (_Float16)fmaxf(acc[ni][mi][3] + bv.w, 0.0f);
            *(f16x4*)(act + m * 1024 + (((n0 >> 3) ^ (m & 7)) << 4) + (n0 & 7) * 2) = h;
        }
    }
}

__global__ __launch_bounds__(1024, 4)
void fused_mlp_kernel(const float* __restrict__ x,
                      const _Float16* __restrict__ wt0, const _Float16* __restrict__ wt1,
                      const _Float16* __restrict__ wt2,
                      const float* __restrict__ b1, const float* __restrict__ b2,
                      const float* __restrict__ b3,
                      float* __restrict__ out)
{
    extern __shared__ char lds[];             // 160 KB: act 128 KB | bwin 32 KB
    char* act  = lds;
    char* bwin = lds + 131072;
    const int tid  = threadIdx.x;
    const int lane = tid & 63;
    const int wid  = tid >> 6;
    const size_t m0 = (size_t)blockIdx.x * 128;

    // ---- stage x slab f32 -> f16 into act [128 rows][1024 B rows, 512 used]
#pragma unroll
    for (int it = 0; it < 4; ++it) {
        const int c   = it * 1024 + tid;      // 4096 16B-chunks
        const int row = c >> 5;
        const int c8  = c & 31;
        const float* src = x + (m0 + row) * 256 + c8 * 8;
        const float4 v0 = *(const float4*)src;
        const float4 v1 = *(const float4*)(src + 4);
        f16x8 h;
        h[0] = (_Float16)v0.x; h[1] = (_Float16)v0.y; h[2] = (_Float16)v0.z; h[3] = (_Float16)v0.w;
        h[4] = (_Float16)v1.x; h[5] = (_Float16)v1.y; h[6] = (_Float16)v1.z; h[7] = (_Float16)v1.w;
        *(f16x8*)(act + row * 1024 + ((c8 ^ (row & 7)) << 4)) = h;
    }
    __syncthreads();

    // wave tiling L1/L2: 16 waves = 2m x 8n of (64m x 64n)
    const int wr = (wid >> 3) * 64;
    const int wc = (wid & 7) * 64;

    // ---- layer 1: z1 = relu(x @ W0 + b1)   [128,256]@[256,512]
    {
        f32x4 acc[4][4] = {};
        mm_phase<256, 32, 4, 4, 512>(act, bwin, wt0, wr, wc, tid, acc);
        store_z(act, b1, wr, wc, lane, acc);  // overwrites x region (reads done)
        __syncthreads();
    }

    // ---- layer 2: z2 = relu(z1 @ W1 + b2)  [128,512]@[512,512]  (in-place)
    {
        f32x4 acc[4][4] = {};
        mm_phase<512, 32, 4, 4, 512>(act, bwin, wt1, wr, wc, tid, acc);
        store_z(act, b2, wr, wc, lane, acc);
        __syncthreads();
    }

    // ---- layer 3: out = z2 @ W2 + b3       [128,512]@[512,256], WK=64
    {
        const int wr3 = (wid & 3) * 32;       // 4m x 4n of (32m x 64n)
        const int wc3 = (wid >> 2) * 64;
        f32x4 acc[4][2] = {};
        mm_phase<512, 64, 4, 2, 256>(act, bwin, wt2, wr3, wc3, tid, acc);

        const int rl = lane & 15;
        const int hi = lane >> 4;
#pragma unroll
        for (int ni = 0; ni < 4; ++ni) {
            const int n0 = wc3 + ni * 16 + hi * 4;
            const float4 bv = *(const float4*)(b3 + n0);
#pragma unroll
            for (int mi = 0; mi < 2; ++mi) {
                const size_t m = m0 + wr3 + mi * 16 + rl;
                f32x4 o;
                o[0] = acc[ni][mi][0] + bv.x;
                o[1] = acc[ni][mi][1] + bv.y;
                o[2] = acc[ni][mi][2] + bv.z;
                o[3] = acc[ni][mi][3] + bv.w;
                *(f32x4*)(out + m * 256 + n0) = o;
            }
        }
    }
}

// ---------------------------------------------------------------------------
// kernel_launch — ws: [wt0 512x256 f16 | wt1 512x512 f16 | wt2 256x512 f16]
// ---------------------------------------------------------------------------
extern "C" void kernel_launch(void* const* d_in, const int* in_sizes, int n_in,
                              void* d_out, int out_size, void* d_ws, size_t ws_size,
                              hipStream_t stream)
{
    const float* x  = (const float*)d_in[0];
    const float* p0 = (const float*)d_in[1];
    const float* p1 = (const float*)d_in[2];
    const float* p2 = (const float*)d_in[3];
    const float* p3 = (const float*)d_in[4];
    const float* b1 = (const float*)d_in[5];
    const float* b2 = (const float*)d_in[6];
    const float* b3 = (const float*)d_in[7];

    char* ws = (char*)d_ws;
    _Float16* wt0 = (_Float16*)(ws);                    // 262144 B
    _Float16* wt1 = (_Float16*)(ws + 262144);           // 524288 B
    _Float16* wt2 = (_Float16*)(ws + 262144 + 524288);  // 262144 B

    synth_weights_kernel<<<2048, 256, 0, stream>>>(p0, p1, p2, p3, wt0, wt1, wt2);

    fused_mlp_kernel<<<BATCH / 128, 1024, 163840, stream>>>(x, wt0, wt1, wt2, b1, b2, b3,
                                                            (float*)d_out);
}